// Round 14
// baseline (302.641 us; speedup 1.0000x reference)
//
#include <hip/hip_runtime.h>
#include <hip/hip_bf16.h>

typedef __attribute__((ext_vector_type(8))) __bf16 bf16x8;
typedef __attribute__((ext_vector_type(4))) float f32x4;

#define SCALE 2.68588886f   // sqrt(5 * log2(e)); acc = 5*log2(e)*cos_sim

static __device__ __forceinline__ float fastexp2(float x) {
#if __has_builtin(__builtin_amdgcn_exp2f)
    return __builtin_amdgcn_exp2f(x);
#else
    return exp2f(x);
#endif
}

// ws layout (extent 4,260,096 proven; used 4,235,524):
//   [0..33024)         float denom_parts[8256]
//   [33024..41216)     float pos_parts[2048]
//   [41216..4235520)   __bf16 outb[16384*128]  (normalized concat, scaled)
//   [4235520..4235524) unsigned done_counter   (reset by normalize each launch)
// No data atomics; one counter atomic per block (last-block finalize).

__global__ __launch_bounds__(256) void normalize_kernel(
    const float* __restrict__ x, const float* __restrict__ xa,
    __bf16* __restrict__ outb, float* __restrict__ pos_parts,
    unsigned* __restrict__ counter, int B)
{
    __shared__ float sdot[4];
    if (blockIdx.x == 0 && threadIdx.x == 0) *counter = 0u;  // graph-replay reset
    int wave = threadIdx.x >> 6;
    int lane = threadIdx.x & 63;
    int row = blockIdx.x * 4 + wave;
    const float2* px = (const float2*)(x  + (size_t)row * 128);
    const float2* pa = (const float2*)(xa + (size_t)row * 128);
    float2 v1 = px[lane];
    float2 v2 = pa[lane];
    float s1 = v1.x * v1.x + v1.y * v1.y;
    float s2 = v2.x * v2.x + v2.y * v2.y;
    float d  = v1.x * v2.x + v1.y * v2.y;
    #pragma unroll
    for (int off = 32; off; off >>= 1) {
        s1 += __shfl_xor(s1, off);
        s2 += __shfl_xor(s2, off);
        d  += __shfl_xor(d,  off);
    }
    float rn1 = rsqrtf(s1) * SCALE;
    float rn2 = rsqrtf(s2) * SCALE;
    union { __bf16 h[2]; unsigned u; } p1, p2;
    p1.h[0] = (__bf16)(v1.x * rn1);
    p1.h[1] = (__bf16)(v1.y * rn1);
    p2.h[0] = (__bf16)(v2.x * rn2);
    p2.h[1] = (__bf16)(v2.y * rn2);
    ((unsigned*)(outb + (size_t)row * 128))[lane]       = p1.u;
    ((unsigned*)(outb + (size_t)(B + row) * 128))[lane] = p2.u;
    if (lane == 0) sdot[wave] = d * rsqrtf(s1) * rsqrtf(s2);  // exact fp32 pos dot
    __syncthreads();
    if (threadIdx.x == 0)
        pos_parts[blockIdx.x] = sdot[0] + sdot[1] + sdot[2] + sdot[3];
}

// One block = one upper-triangular 128x128 tile of G = out*out^T.
//
// r5: supertile + XCD-chunk swizzle fixed read locality (FETCH 95->19 MB).
// r6: 4-phase K=32 double-buffered LDS (FETCH 12 MB, WRITE 0.26 MB).
// r7/r12 (BEST sim, 57-60 us): 64B-row swizzle, conflicts 0; VALU ~52%,
//     MFMA ~24% (14 us floor), HBM 2.7%, occupancy 35%.
// r8 FAILED: acc read after epilogue loop -> spill. r10 FAILED: (512,8)
//     reg-cap -> spill. r13: (512,4) occupancy 54% but MORE per-wave VALU
//     -> neutral-worse. Occupancy lever refuted both ways; VALU-issue +
//     dependency bound. sim structure frozen at r12.
// r14: total = sim + ~63 us across ALL rounds -> attack launch overhead:
//     finalize folded into sim via last-block counter pattern (fence +
//     atomic; deterministic reduce order). finalize_kernel deleted.
//
// r1 lesson: no global_load_lds with scattered sources (HBM blowup).
__global__ __launch_bounds__(256, 4) void sim_kernel(
    const __bf16* __restrict__ outb, const int* __restrict__ hq,
    const int* __restrict__ nq, float* __restrict__ denom_parts,
    const float* __restrict__ pos_parts, float* __restrict__ out,
    unsigned* __restrict__ counter, float invB, int np)
{
    // XCD-chunk swizzle: each XCD gets a contiguous wgid range (8256 = 8*1032).
    int wgid = (blockIdx.x & 7) * 1032 + (blockIdx.x >> 3);

    // Supertile decode: supertile rows I=0..7, row I = diag(136) + (7-I)*256.
    int rem = wgid;
    int I = 0;
    #pragma unroll 1
    while (true) {
        int rc = 136 + (7 - I) * 256;
        if (rem < rc) break;
        rem -= rc; ++I;
    }
    int bi, bj;
    if (rem < 136) {
        // diagonal supertile (I,I): triangular 16-row decode, row ti has 16-ti
        int ti = 0;
        #pragma unroll 1
        while (rem >= 16 - ti) { rem -= 16 - ti; ++ti; }
        bi = I * 16 + ti;
        bj = I * 16 + ti + rem;
    } else {
        rem -= 136;
        int J = I + 1 + (rem >> 8);
        int local = rem & 255;
        bi = I * 16 + (local >> 4);
        bj = J * 16 + (local & 15);
    }

    // Double-buffered 32-col half-tiles: [buf][A/B][128 rows * 4 chunks]
    __shared__ float4 sbuf[2][2][512];   // 32 KB
    __shared__ unsigned sMU[128];   // bits_r | onehot(h_r)<<10
    __shared__ unsigned sMV[128];   // onehot(h_c) | bits_c<<10
    __shared__ float red[8];
    __shared__ int isLast;

    int tid = threadIdx.x;

    const float4* gA = (const float4*)(outb + (size_t)bi * 128 * 128);
    const float4* gB = (const float4*)(outb + (size_t)bj * 128 * 128);

    // Staging geometry: 512 16B chunks per matrix per phase; thread handles
    // chunk tid (row tid>>2, c tid&3) and chunk tid+256 (row +64, same c).
    // LDS pos = c ^ ((row>>1)&3): with 64B rows, slot = 4*(row&1) + pos
    // covers all 8 bank-slots over any 8 consecutive rows (r7-proven).
    int r0 = tid >> 2, c0 = tid & 3;
    int g0 = r0 * 16 + c0;            // global chunk idx, + p*4 per phase
    int g1 = g0 + 64 * 16;
    int s0 = r0 * 4 + (c0 ^ ((r0 >> 1) & 3));
    int s1 = s0 + 64 * 4;             // ((r0+64)>>1)&3 == (r0>>1)&3

    // Issue phase-0 loads first; mask build overlaps their latency.
    float4 la0 = gA[g0], la1 = gA[g1];
    float4 lb0 = gB[g0], lb1 = gB[g1];

    // Build masks directly from nq/hq (L2-hot): 128 threads rows, 128 cols.
    {
        int half = tid >> 7;
        int idx = tid & 127;
        int row = (half ? bj : bi) * 128 + idx;
        const int* p = nq + (size_t)row * 10;
        unsigned b = 0;
        #pragma unroll
        for (int k = 0; k < 10; ++k) b |= 1u << (p[k] & 31);
        unsigned h = (unsigned)hq[row];
        if (half) sMV[idx] = (1u << h) | (b << 10);
        else      sMU[idx] = b | (1u << (10 + h));
        // popc(sMU[r] & sMV[c]) = (bits_r>>h_c & 1) + (bits_c>>h_r & 1)
    }

    sbuf[0][0][s0] = la0; sbuf[0][0][s1] = la1;
    sbuf[0][1][s0] = lb0; sbuf[0][1][s1] = lb1;
    __syncthreads();

    int wave = tid >> 6, lane = tid & 63;
    int wr = (wave >> 1) * 64;   // wave's 64x64 subtile origin
    int wc = (wave & 1) * 64;
    int lrow = lane & 15, quad = lane >> 4;

    f32x4 acc[4][4] = {};

    #pragma unroll
    for (int p = 0; p < 4; ++p) {
        int pb = p & 1;
        if (p < 3) {   // issue next-phase loads: latency hides under MFMA
            la0 = gA[g0 + (p + 1) * 4]; la1 = gA[g1 + (p + 1) * 4];
            lb0 = gB[g0 + (p + 1) * 4]; lb1 = gB[g1 + (p + 1) * 4];
        }
        const __bf16* Ab = (const __bf16*)sbuf[pb][0];
        const __bf16* Bb = (const __bf16*)sbuf[pb][1];
        bf16x8 a[4], b[4];
        #pragma unroll
        for (int m = 0; m < 4; ++m) {
            int r = wr + m * 16 + lrow;
            a[m] = *(const bf16x8*)&Ab[r * 32 + ((quad ^ ((r >> 1) & 3)) << 3)];
        }
        #pragma unroll
        for (int n = 0; n < 4; ++n) {
            int r = wc + n * 16 + lrow;
            b[n] = *(const bf16x8*)&Bb[r * 32 + ((quad ^ ((r >> 1) & 3)) << 3)];
        }
        #pragma unroll
        for (int m = 0; m < 4; ++m)
            #pragma unroll
            for (int n = 0; n < 4; ++n)
                acc[m][n] = __builtin_amdgcn_mfma_f32_16x16x32_bf16(
                    a[m], b[n], acc[m][n], 0, 0, 0);
        if (p < 3) {   // write next phase into the other buffer
            sbuf[pb ^ 1][0][s0] = la0; sbuf[pb ^ 1][0][s1] = la1;
            sbuf[pb ^ 1][1][s0] = lb0; sbuf[pb ^ 1][1][s1] = lb1;
            __syncthreads();   // next phase's buffer ready; prev buffer free
        }
    }

    // Hoist masks to registers (C/D layout: col = lane&15, row = quad*4+reg).
    unsigned mv[4];
    uint4 mu[4];
    #pragma unroll
    for (int n = 0; n < 4; ++n) mv[n] = sMV[wc + n * 16 + lrow];
    #pragma unroll
    for (int m = 0; m < 4; ++m)
        mu[m] = *(const uint4*)&sMU[wr + m * 16 + quad * 4];

    // Diagonal kill multiplier (r8 rule: acc dies inside this single loop).
    bool diag = (bi == bj);
    bool lane_diag = diag && (wr == wc) && ((lrow >> 2) == quad);
    int rd = lrow & 3;
    float wk[4];
    #pragma unroll
    for (int r = 0; r < 4; ++r)
        wk[r] = (lane_diag && r == rd) ? 0.0f : 1.0f;

    float ls[4] = {0.0f, 0.0f, 0.0f, 0.0f};   // 4 chains: break fmac latency
    #pragma unroll
    for (int m = 0; m < 4; ++m) {
        unsigned mur[4] = {mu[m].x, mu[m].y, mu[m].z, mu[m].w};
        #pragma unroll
        for (int n = 0; n < 4; ++n) {
            #pragma unroll
            for (int r = 0; r < 4; ++r) {
                float w = (float)__popc(mur[r] & mv[n]);
                if (m == n) w *= wk[r];   // static test: folds at compile time
                ls[r] += fastexp2(acc[m][n][r]) * w;
            }
        }
    }
    float lsum = (ls[0] + ls[1]) + (ls[2] + ls[3]);
    if (diag) lsum *= 0.5f;   // diag tile counts each unordered pair twice

    #pragma unroll
    for (int off = 32; off; off >>= 1) lsum += __shfl_down(lsum, off);
    if (lane == 0) red[wave] = lsum;
    __syncthreads();
    if (tid == 0) {
        denom_parts[blockIdx.x] = red[0] + red[1] + red[2] + red[3];
        __threadfence();                       // publish before counting
        unsigned done = atomicAdd(counter, 1u);
        isLast = (done == gridDim.x - 1) ? 1 : 0;
    }
    __syncthreads();

    // Last-finishing block performs the final reduction (deterministic
    // order regardless of WHICH block is last). Saves the finalize launch.
    if (isLast) {
        __threadfence();   // acquire: see all other blocks' denom_parts
        float d = 0.0f, pp = 0.0f;
        int nb = gridDim.x;
        for (int i = tid; i < nb; i += 256) d += denom_parts[i];
        for (int i = tid; i < np; i += 256) pp += pos_parts[i];
        #pragma unroll
        for (int off = 32; off; off >>= 1) {
            d  += __shfl_down(d,  off);
            pp += __shfl_down(pp, off);
        }
        if (lane == 0) { red[wave] = d; red[4 + wave] = pp; }
        __syncthreads();
        if (tid == 0) {
            float D = (red[0] + red[1]) + (red[2] + red[3]);
            float P = (red[4] + red[5]) + (red[6] + red[7]);
            out[0] = logf(D) - 5.0f * P * invB;
        }
    }
}

extern "C" void kernel_launch(void* const* d_in, const int* in_sizes, int n_in,
                              void* d_out, int out_size, void* d_ws, size_t ws_size,
                              hipStream_t stream) {
    const float* x  = (const float*)d_in[0];
    const float* xa = (const float*)d_in[1];
    const int* hq   = (const int*)d_in[2];
    const int* nq   = (const int*)d_in[3];
    int B = in_sizes[0] / 128;   // 8192
    int N = 2 * B;               // 16384
    int T = N / 128;             // 128 tile-rows
    int nblocks = T * (T + 1) / 2;   // 8256 upper-triangular tiles

    char* ws = (char*)d_ws;
    float* denom_parts = (float*)ws;                       // 8256 f32
    float* pos_parts   = (float*)(ws + 33024);             // 2048 f32
    __bf16* outb       = (__bf16*)(ws + 41216);            // N*128 bf16
    unsigned* counter  = (unsigned*)(ws + 4235520);        // 1 u32

    normalize_kernel<<<B / 4, 256, 0, stream>>>(x, xa, outb, pos_parts,
                                                counter, B);
    sim_kernel<<<nblocks, 256, 0, stream>>>(outb, hq, nq, denom_parts,
                                            pos_parts, (float*)d_out, counter,
                                            1.0f / (float)B, B / 4);
}

// Round 15
// 122.214 us; speedup vs baseline: 2.4763x; 2.4763x over previous
//
#include <hip/hip_runtime.h>
#include <hip/hip_bf16.h>

typedef __attribute__((ext_vector_type(8))) __bf16 bf16x8;
typedef __attribute__((ext_vector_type(4))) float f32x4;

#define SCALE 2.68588886f   // sqrt(5 * log2(e)); acc = 5*log2(e)*cos_sim

static __device__ __forceinline__ float fastexp2(float x) {
#if __has_builtin(__builtin_amdgcn_exp2f)
    return __builtin_amdgcn_exp2f(x);
#else
    return exp2f(x);
#endif
}

// ws layout (total 4,235,520 B):
//   [0..33024)         float denom_parts[8256]
//   [33024..41216)     float pos_parts[2048]
//   [41216..4235520)   __bf16 outb[16384*128]  (normalized concat, scaled)
// No atomics anywhere: every slot is written by exactly one block.

__global__ __launch_bounds__(256) void normalize_kernel(
    const float* __restrict__ x, const float* __restrict__ xa,
    __bf16* __restrict__ outb, float* __restrict__ pos_parts, int B)
{
    __shared__ float sdot[4];
    int wave = threadIdx.x >> 6;
    int lane = threadIdx.x & 63;
    int row = blockIdx.x * 4 + wave;
    const float2* px = (const float2*)(x  + (size_t)row * 128);
    const float2* pa = (const float2*)(xa + (size_t)row * 128);
    float2 v1 = px[lane];
    float2 v2 = pa[lane];
    float s1 = v1.x * v1.x + v1.y * v1.y;
    float s2 = v2.x * v2.x + v2.y * v2.y;
    float d  = v1.x * v2.x + v1.y * v2.y;
    #pragma unroll
    for (int off = 32; off; off >>= 1) {
        s1 += __shfl_xor(s1, off);
        s2 += __shfl_xor(s2, off);
        d  += __shfl_xor(d,  off);
    }
    float rn1 = rsqrtf(s1) * SCALE;
    float rn2 = rsqrtf(s2) * SCALE;
    union { __bf16 h[2]; unsigned u; } p1, p2;
    p1.h[0] = (__bf16)(v1.x * rn1);
    p1.h[1] = (__bf16)(v1.y * rn1);
    p2.h[0] = (__bf16)(v2.x * rn2);
    p2.h[1] = (__bf16)(v2.y * rn2);
    ((unsigned*)(outb + (size_t)row * 128))[lane]       = p1.u;
    ((unsigned*)(outb + (size_t)(B + row) * 128))[lane] = p2.u;
    if (lane == 0) sdot[wave] = d * rsqrtf(s1) * rsqrtf(s2);  // exact fp32 pos dot
    __syncthreads();
    if (threadIdx.x == 0)
        pos_parts[blockIdx.x] = sdot[0] + sdot[1] + sdot[2] + sdot[3];
}

// One block = one upper-triangular 128x128 tile of G = out*out^T.
//
// Final structure (r12-verified, 122.99 us total / ~60 us sim):
// r5: supertile + XCD-chunk swizzle fixed read locality (FETCH 95->19 MB).
// r6: 4-phase K=32 double-buffered LDS (FETCH 12 MB, WRITE 0.26 MB).
// r7: 64B-row swizzle pos = c ^ ((r>>1)&3): bank conflicts 4.2M -> 0.
// r11/r12: uint4 mask hoist + packed normalize stores (neutral-positive).
//
// Refuted levers (do not retry):
// r1:  global_load_lds with scattered sources -> 6.5x HBM blowup.
// r3/r8: epilogue duplication / acc read after the epilogue loop ->
//        scratch spill (acc must die inside the single epilogue loop).
// r10: __launch_bounds__(512,8) reg-cap -> 600 MB spill (2nd arg is a
//      register-cap contract; this tile needs ~128 regs = 4 waves/SIMD).
// r13: (512,4) raised occupancy 35->54% but added per-wave VALU -> neutral.
// r14: last-block finalize fusion: per-block __threadfence() invalidates
//      per-XCD L2 -> L2-resident panels fell to L3, sim 60->247 us. Also
//      proved the ~60 us total-minus-sim gap is fixed harness overhead.
__global__ __launch_bounds__(256, 4) void sim_kernel(
    const __bf16* __restrict__ outb, const int* __restrict__ hq,
    const int* __restrict__ nq, float* __restrict__ denom_parts)
{
    // XCD-chunk swizzle: each XCD gets a contiguous wgid range (8256 = 8*1032).
    int wgid = (blockIdx.x & 7) * 1032 + (blockIdx.x >> 3);

    // Supertile decode: supertile rows I=0..7, row I = diag(136) + (7-I)*256.
    int rem = wgid;
    int I = 0;
    #pragma unroll 1
    while (true) {
        int rc = 136 + (7 - I) * 256;
        if (rem < rc) break;
        rem -= rc; ++I;
    }
    int bi, bj;
    if (rem < 136) {
        // diagonal supertile (I,I): triangular 16-row decode, row ti has 16-ti
        int ti = 0;
        #pragma unroll 1
        while (rem >= 16 - ti) { rem -= 16 - ti; ++ti; }
        bi = I * 16 + ti;
        bj = I * 16 + ti + rem;
    } else {
        rem -= 136;
        int J = I + 1 + (rem >> 8);
        int local = rem & 255;
        bi = I * 16 + (local >> 4);
        bj = J * 16 + (local & 15);
    }

    // Double-buffered 32-col half-tiles: [buf][A/B][128 rows * 4 chunks]
    __shared__ float4 sbuf[2][2][512];   // 32 KB
    __shared__ unsigned sMU[128];   // bits_r | onehot(h_r)<<10
    __shared__ unsigned sMV[128];   // onehot(h_c) | bits_c<<10
    __shared__ float red[4];

    int tid = threadIdx.x;

    const float4* gA = (const float4*)(outb + (size_t)bi * 128 * 128);
    const float4* gB = (const float4*)(outb + (size_t)bj * 128 * 128);

    // Staging geometry: 512 16B chunks per matrix per phase; thread handles
    // chunk tid (row tid>>2, c tid&3) and chunk tid+256 (row +64, same c).
    // LDS pos = c ^ ((row>>1)&3): with 64B rows, slot = 4*(row&1) + pos
    // covers all 8 bank-slots over any 8 consecutive rows (r7-proven).
    int r0 = tid >> 2, c0 = tid & 3;
    int g0 = r0 * 16 + c0;            // global chunk idx, + p*4 per phase
    int g1 = g0 + 64 * 16;
    int s0 = r0 * 4 + (c0 ^ ((r0 >> 1) & 3));
    int s1 = s0 + 64 * 4;             // ((r0+64)>>1)&3 == (r0>>1)&3

    // Issue phase-0 loads first; mask build overlaps their latency.
    float4 la0 = gA[g0], la1 = gA[g1];
    float4 lb0 = gB[g0], lb1 = gB[g1];

    // Build masks directly from nq/hq (L2-hot): 128 threads rows, 128 cols.
    {
        int half = tid >> 7;
        int idx = tid & 127;
        int row = (half ? bj : bi) * 128 + idx;
        const int* p = nq + (size_t)row * 10;
        unsigned b = 0;
        #pragma unroll
        for (int k = 0; k < 10; ++k) b |= 1u << (p[k] & 31);
        unsigned h = (unsigned)hq[row];
        if (half) sMV[idx] = (1u << h) | (b << 10);
        else      sMU[idx] = b | (1u << (10 + h));
        // popc(sMU[r] & sMV[c]) = (bits_r>>h_c & 1) + (bits_c>>h_r & 1)
    }

    sbuf[0][0][s0] = la0; sbuf[0][0][s1] = la1;
    sbuf[0][1][s0] = lb0; sbuf[0][1][s1] = lb1;
    __syncthreads();

    int wave = tid >> 6, lane = tid & 63;
    int wr = (wave >> 1) * 64;   // wave's 64x64 subtile origin
    int wc = (wave & 1) * 64;
    int lrow = lane & 15, quad = lane >> 4;

    f32x4 acc[4][4] = {};

    #pragma unroll
    for (int p = 0; p < 4; ++p) {
        int pb = p & 1;
        if (p < 3) {   // issue next-phase loads: latency hides under MFMA
            la0 = gA[g0 + (p + 1) * 4]; la1 = gA[g1 + (p + 1) * 4];
            lb0 = gB[g0 + (p + 1) * 4]; lb1 = gB[g1 + (p + 1) * 4];
        }
        const __bf16* Ab = (const __bf16*)sbuf[pb][0];
        const __bf16* Bb = (const __bf16*)sbuf[pb][1];
        bf16x8 a[4], b[4];
        #pragma unroll
        for (int m = 0; m < 4; ++m) {
            int r = wr + m * 16 + lrow;
            a[m] = *(const bf16x8*)&Ab[r * 32 + ((quad ^ ((r >> 1) & 3)) << 3)];
        }
        #pragma unroll
        for (int n = 0; n < 4; ++n) {
            int r = wc + n * 16 + lrow;
            b[n] = *(const bf16x8*)&Bb[r * 32 + ((quad ^ ((r >> 1) & 3)) << 3)];
        }
        #pragma unroll
        for (int m = 0; m < 4; ++m)
            #pragma unroll
            for (int n = 0; n < 4; ++n)
                acc[m][n] = __builtin_amdgcn_mfma_f32_16x16x32_bf16(
                    a[m], b[n], acc[m][n], 0, 0, 0);
        if (p < 3) {   // write next phase into the other buffer
            sbuf[pb ^ 1][0][s0] = la0; sbuf[pb ^ 1][0][s1] = la1;
            sbuf[pb ^ 1][1][s0] = lb0; sbuf[pb ^ 1][1][s1] = lb1;
            __syncthreads();   // next phase's buffer ready; prev buffer free
        }
    }

    // Hoist masks to registers (C/D layout: col = lane&15, row = quad*4+reg).
    // mu rows are 4 consecutive dwords at a 16B-aligned offset -> uint4.
    unsigned mv[4];
    uint4 mu[4];
    #pragma unroll
    for (int n = 0; n < 4; ++n) mv[n] = sMV[wc + n * 16 + lrow];
    #pragma unroll
    for (int m = 0; m < 4; ++m)
        mu[m] = *(const uint4*)&sMU[wr + m * 16 + quad * 4];

    // Diagonal kill multiplier: element (m,n,r) is on the matrix diagonal
    // iff bi==bj, wr==wc, m==n, and quad*4+r == lrow. Precompute per-lane
    // wk[r] so the hot loop needs only 16 v_mul (m==n cases), no branch.
    // (r8 rule: acc is consumed only inside this single loop.)
    bool diag = (bi == bj);
    bool lane_diag = diag && (wr == wc) && ((lrow >> 2) == quad);
    int rd = lrow & 3;
    float wk[4];
    #pragma unroll
    for (int r = 0; r < 4; ++r)
        wk[r] = (lane_diag && r == rd) ? 0.0f : 1.0f;

    float ls[4] = {0.0f, 0.0f, 0.0f, 0.0f};   // 4 chains: break fmac latency
    #pragma unroll
    for (int m = 0; m < 4; ++m) {
        unsigned mur[4] = {mu[m].x, mu[m].y, mu[m].z, mu[m].w};
        #pragma unroll
        for (int n = 0; n < 4; ++n) {
            #pragma unroll
            for (int r = 0; r < 4; ++r) {
                float w = (float)__popc(mur[r] & mv[n]);
                if (m == n) w *= wk[r];   // static test: folds at compile time
                ls[r] += fastexp2(acc[m][n][r]) * w;
            }
        }
    }
    float lsum = (ls[0] + ls[1]) + (ls[2] + ls[3]);
    if (diag) lsum *= 0.5f;   // diag tile counts each unordered pair twice

    #pragma unroll
    for (int off = 32; off; off >>= 1) lsum += __shfl_down(lsum, off);
    if (lane == 0) red[wave] = lsum;
    __syncthreads();
    if (tid == 0)
        denom_parts[blockIdx.x] = red[0] + red[1] + red[2] + red[3];
}

__global__ __launch_bounds__(1024) void finalize_kernel(
    const float* __restrict__ denom_parts, const float* __restrict__ pos_parts,
    float* __restrict__ out, float invB, int nd, int np)
{
    __shared__ float sred[32];
    int tid = threadIdx.x;
    float d = 0.0f, p = 0.0f;
    for (int i = tid; i < nd; i += 1024) d += denom_parts[i];
    for (int i = tid; i < np; i += 1024) p += pos_parts[i];
    #pragma unroll
    for (int off = 32; off; off >>= 1) {
        d += __shfl_down(d, off);
        p += __shfl_down(p, off);
    }
    int wv = tid >> 6, ln = tid & 63;
    if (ln == 0) { sred[wv] = d; sred[16 + wv] = p; }
    __syncthreads();
    if (tid == 0) {
        float D = 0.0f, P = 0.0f;
        #pragma unroll
        for (int i = 0; i < 16; ++i) { D += sred[i]; P += sred[16 + i]; }
        out[0] = logf(D) - 5.0f * P * invB;
    }
}

extern "C" void kernel_launch(void* const* d_in, const int* in_sizes, int n_in,
                              void* d_out, int out_size, void* d_ws, size_t ws_size,
                              hipStream_t stream) {
    const float* x  = (const float*)d_in[0];
    const float* xa = (const float*)d_in[1];
    const int* hq   = (const int*)d_in[2];
    const int* nq   = (const int*)d_in[3];
    int B = in_sizes[0] / 128;   // 8192
    int N = 2 * B;               // 16384
    int T = N / 128;             // 128 tile-rows
    int nblocks = T * (T + 1) / 2;   // 8256 upper-triangular tiles

    char* ws = (char*)d_ws;
    float* denom_parts = (float*)ws;                       // 8256 f32
    float* pos_parts   = (float*)(ws + 33024);             // 2048 f32
    __bf16* outb       = (__bf16*)(ws + 41216);            // N*128 bf16

    normalize_kernel<<<B / 4, 256, 0, stream>>>(x, xa, outb, pos_parts, B);
    sim_kernel<<<nblocks, 256, 0, stream>>>(outb, hq, nq, denom_parts);
    finalize_kernel<<<1, 1024, 0, stream>>>(denom_parts, pos_parts,
                                            (float*)d_out, 1.0f / (float)B,
                                            nblocks, B / 4);
}